// Round 8
// baseline (704.905 us; speedup 1.0000x reference)
//
#include <hip/hip_runtime.h>

#define NTOT 65536      // 16*64*64 vectors
#define KC   8192       // codebook size
#define DV   64         // embedding dim
#define ZQN  4194304    // z_q elements
#define NSPL 4          // k-slices
#define KSL  2048       // codes per slice
#define TILE 128        // codes per LDS tile
#define NTILE 16        // tiles per slice
#define CAP  12         // candidate entries per (n, slice)
#define THF  4.5e-5f    // append margin (>= filter threshold 42/2^20)
#define SLACK 40        // E1 enc filter slack (units of 2^-20; ~4.0e-5 >= TH 3e-5)

typedef unsigned int u32;
typedef unsigned long long u64;
typedef unsigned short ushort;
typedef short short8 __attribute__((ext_vector_type(8)));   // 8 bf16
typedef float float4v __attribute__((ext_vector_type(4)));  // MFMA acc

__device__ __forceinline__ short f2bf(float x) {           // fp32->bf16 RNE
    u32 u = __float_as_uint(x);
    u32 r = (u + 0x7fffu + ((u >> 16) & 1u)) >> 16;
    return (short)r;
}

// Bit-exact numpy fp32 distance (VERIFIED bit-exact rounds 3-7):
// d = fl(fl(A+B) - 2*dot), dot in c_einsum SSE3-baseline order.
__device__ __forceinline__ float exact_d(float A, float B,
                                         const float* __restrict__ zr,
                                         const float* __restrict__ e) {
#pragma clang fp contract(off)
    float u0 = 0.f, u1 = 0.f, u2 = 0.f, u3 = 0.f;
#pragma unroll
    for (int i = 0; i < 4; ++i) {
        const int t = 16 * i;
        u0 = (zr[t+0]*e[t+0]) + ((zr[t+4]*e[t+4]) + ((zr[t+8]*e[t+8]) + ((zr[t+12]*e[t+12]) + u0)));
        u1 = (zr[t+1]*e[t+1]) + ((zr[t+5]*e[t+5]) + ((zr[t+9]*e[t+9]) + ((zr[t+13]*e[t+13]) + u1)));
        u2 = (zr[t+2]*e[t+2]) + ((zr[t+6]*e[t+6]) + ((zr[t+10]*e[t+10]) + ((zr[t+14]*e[t+14]) + u2)));
        u3 = (zr[t+3]*e[t+3]) + ((zr[t+7]*e[t+7]) + ((zr[t+11]*e[t+11]) + ((zr[t+15]*e[t+15]) + u3)));
    }
    float dot = (u0 + u1) + (u2 + u3);
    return (A + B) - (2.0f * dot);
}

// prep: fragment-order-shuffled bf16 codebook (verified round 7) + ||e||^2
// + zero lacc/oflowCnt.
__global__ __launch_bounds__(256) void vq_prep(
    const float* __restrict__ emb, float* __restrict__ nrm,
    double* __restrict__ lacc, u32* __restrict__ oflowCnt,
    ushort* __restrict__ ebs) {
    const int tid = blockIdx.x * 256 + threadIdx.x;    // 65536 threads
    const int t = tid >> 10, r = tid & 1023;
    const int s = r >> 7, r2 = r & 127, h = r2 >> 6, l = r2 & 63;
    const int q = l >> 4, c = l & 15;
    const float* src = emb + (size_t)((t * 128 + s * 16 + c) * 64 + h * 32 + q * 8);
    short8 v;
#pragma unroll
    for (int j = 0; j < 8; ++j) v[j] = f2bf(src[j]);
    *reinterpret_cast<short8*>(ebs + (size_t)tid * 8) = v;
    if (tid < KC) {
        double sacc = 0.0;
#pragma unroll
        for (int d = 0; d < DV; ++d) {
            double x = (double)emb[(size_t)tid * DV + d];
            sacc = fma(x, x, sacc);
        }
        nrm[tid] = (float)sacc;
    }
    if (tid == 0) { *lacc = 0.0; *oflowCnt = 0u; }
}

// Single MFMA screen pass. Warm loop (tiles 0-1) tightens rmt; main loop
// (tiles 0-15) appends cells with m4 >= rmt = runmax - THF (runmax <= final
// max -> provable superset of cells within THF of the slice max). Appends:
// LDS-atomic position -> direct global store (enc16|cell9). No register
// lists, no dynamic indexing -> no scratch. Layouts verified rounds 5-7.
__global__ __launch_bounds__(256, 4) void vq_pass(
    const float* __restrict__ z, const ushort* __restrict__ ebs,
    u32* __restrict__ cnt, u32* __restrict__ cand) {
    __shared__ ushort tileS[TILE * DV];     // 16 KB
    __shared__ u32 lcnt[256];
    const int tid = threadIdx.x;
    const int lane = tid & 63, wv = tid >> 6;
    const int nblk = blockIdx.x & 255, ks = blockIdx.x >> 8;
    const int nb = nblk * 256 + wv * 64;
    const int col = lane & 15, quad = lane >> 4;
    const int nlo = nb + col;

    lcnt[tid] = 0u;

    // z B-frags in VGPRs (bitwise-identical conversion, rounds 5-7)
    short8 zf[4][2];
#pragma unroll
    for (int ns = 0; ns < 4; ++ns) {
        int n = nlo + ns * 16;
        const float* zp = z + (size_t)(n >> 12) * 262144 + (n & 4095);
#pragma unroll
        for (int t2 = 0; t2 < 2; ++t2)
#pragma unroll
            for (int j = 0; j < 8; ++j)
                zf[ns][t2][j] = f2bf(zp[(size_t)(t2 * 32 + quad * 8 + j) * 4096]);
    }

    // per-ns candidate-list ids (LDS slot + global base)
    int nl[4]; u32 cb[4];
#pragma unroll
    for (int ns = 0; ns < 4; ++ns) {
        nl[ns] = wv * 64 + ns * 16 + col;
        cb[ns] = (u32)(ks * NTOT + nblk * 256 + nl[ns]) * CAP;
    }

    float rmt[4] = {-1e30f, -1e30f, -1e30f, -1e30f};
    const char* gs = (const char*)ebs + (size_t)ks * (KSL * DV * 2);

    // ---- warm loop: tiles 0,1 — rmt only ----
    int4 pre[4];
#pragma unroll
    for (int j = 0; j < 4; ++j)
        pre[j] = *reinterpret_cast<const int4*>(gs + j * 4096 + tid * 16);
    for (int t = 0; t < 2; ++t) {
        __syncthreads();
#pragma unroll
        for (int j = 0; j < 4; ++j)
            *reinterpret_cast<int4*>((char*)tileS + j * 4096 + tid * 16) = pre[j];
        __syncthreads();
#pragma unroll
        for (int j = 0; j < 4; ++j)
            pre[j] = *reinterpret_cast<const int4*>(
                gs + (size_t)((t + 1) & 1) * 16384 + j * 4096 + tid * 16);
#pragma unroll
        for (int s = 0; s < 8; ++s) {
            const char* tb = (const char*)tileS + s * 2048;
            short8 a0 = *reinterpret_cast<const short8*>(tb + lane * 16);
            short8 a1 = *reinterpret_cast<const short8*>(tb + 1024 + lane * 16);
#pragma unroll
            for (int ns = 0; ns < 4; ++ns) {
                float4v acc = {0.f, 0.f, 0.f, 0.f};
                acc = __builtin_amdgcn_mfma_f32_16x16x32_bf16(a0, zf[ns][0], acc, 0, 0, 0);
                acc = __builtin_amdgcn_mfma_f32_16x16x32_bf16(a1, zf[ns][1], acc, 0, 0, 0);
                float m4 = fmaxf(fmaxf(acc[0], acc[1]), fmaxf(acc[2], acc[3]));
                rmt[ns] = fmaxf(rmt[ns], m4 - THF);
            }
        }
#pragma unroll
        for (int ns = 0; ns < 4; ++ns) {
            float v = rmt[ns];
            v = fmaxf(v, __shfl_xor(v, 16));
            v = fmaxf(v, __shfl_xor(v, 32));
            rmt[ns] = v;
        }
    }

    // ---- main loop: tiles 0..15 — append cells within margin ----
#pragma unroll
    for (int j = 0; j < 4; ++j)
        pre[j] = *reinterpret_cast<const int4*>(gs + j * 4096 + tid * 16);
    for (int t = 0; t < NTILE; ++t) {
        __syncthreads();
#pragma unroll
        for (int j = 0; j < 4; ++j)
            *reinterpret_cast<int4*>((char*)tileS + j * 4096 + tid * 16) = pre[j];
        __syncthreads();
        if (t < NTILE - 1) {
#pragma unroll
            for (int j = 0; j < 4; ++j)
                pre[j] = *reinterpret_cast<const int4*>(
                    gs + (size_t)(t + 1) * 16384 + j * 4096 + tid * 16);
        }
#pragma unroll
        for (int s = 0; s < 8; ++s) {
            const char* tb = (const char*)tileS + s * 2048;
            short8 a0 = *reinterpret_cast<const short8*>(tb + lane * 16);
            short8 a1 = *reinterpret_cast<const short8*>(tb + 1024 + lane * 16);
#pragma unroll
            for (int ns = 0; ns < 4; ++ns) {
                float4v acc = {0.f, 0.f, 0.f, 0.f};
                acc = __builtin_amdgcn_mfma_f32_16x16x32_bf16(a0, zf[ns][0], acc, 0, 0, 0);
                acc = __builtin_amdgcn_mfma_f32_16x16x32_bf16(a1, zf[ns][1], acc, 0, 0, 0);
                float m4 = fmaxf(fmaxf(acc[0], acc[1]), fmaxf(acc[2], acc[3]));
                if (m4 >= rmt[ns]) {                       // margin hit (rare)
                    u32 pos = atomicAdd(&lcnt[nl[ns]], 1u);
                    if (pos < CAP) {
                        int ienc = (int)(m4 * 1048576.0f) + 32768;
                        ienc = min(max(ienc, 0), 65535);
                        u32 cell = (u32)(((t * 8 + s) << 2) | quad);
                        cand[cb[ns] + pos] = ((u32)ienc << 16) | cell;
                    }
                }
                rmt[ns] = fmaxf(rmt[ns], m4 - THF);
            }
        }
#pragma unroll
        for (int ns = 0; ns < 4; ++ns) {
            float v = rmt[ns];
            v = fmaxf(v, __shfl_xor(v, 16));
            v = fmaxf(v, __shfl_xor(v, 32));
            rmt[ns] = v;
        }
    }

    __syncthreads();
    cnt[(size_t)ks * NTOT + nblk * 256 + tid] = lcnt[tid];
}

// E1: enc-filter entries, exact (numpy-bit-identical) rescore -> index.
// Overflowed n are deferred to E1b via an overflow list.
__global__ __launch_bounds__(256) void vq_e1(
    const float* __restrict__ z, const float* __restrict__ emb,
    const float* __restrict__ nrm, const u32* __restrict__ cnt,
    const u32* __restrict__ cand, int* __restrict__ idxw,
    float* __restrict__ out, u32* __restrict__ oflowCnt,
    int* __restrict__ oflowList) {
    const int n = blockIdx.x * 256 + threadIdx.x;
    u32 c[NSPL];
    bool oflow = false;
#pragma unroll
    for (int s = 0; s < NSPL; ++s) {
        c[s] = cnt[(size_t)s * NTOT + n];
        if (c[s] > CAP) { oflow = true; c[s] = CAP; }
    }
    if (oflow) {
        u32 p = atomicAdd(oflowCnt, 1u);
        oflowList[p] = n;
        idxw[n] = 0;
        out[(size_t)ZQN + 1 + n] = 0.f;   // E1b overwrites
        return;
    }
    // enc max across all entries
    u32 emax = 0u;
    for (int s = 0; s < NSPL; ++s)
        for (u32 j = 0; j < c[s]; ++j) {
            u32 e = cand[((size_t)s * NTOT + n) * CAP + j];
            if (e > emax) emax = e;
        }
    u32 ethr = ((emax >> 16) > SLACK ? ((emax >> 16) - SLACK) : 0u) << 16;

    const float* zp = z + (size_t)(n >> 12) * 262144 + (n & 4095);
    float zr[DV];
#pragma unroll
    for (int d = 0; d < DV; ++d) zr[d] = zp[(size_t)d * 4096];
    double ad = 0.0;
#pragma unroll
    for (int d = 0; d < DV; ++d) ad = fma((double)zr[d], (double)zr[d], ad);
    const float A = (float)ad;

    float dmin = 1e30f;
    int kmin = 0x7fffffff;
    for (int s = 0; s < NSPL; ++s)
        for (u32 j = 0; j < c[s]; ++j) {
            u32 e = cand[((size_t)s * NTOT + n) * CAP + j];
            if (e < ethr) continue;                       // filtered out
            u32 cell = e & 0xffffu;
            int base = s * KSL + (int)((cell >> 2) * 16 + (cell & 3) * 4);
#pragma unroll
            for (int r = 0; r < 4; ++r) {
                int k = base + r;
                float d = exact_d(A, nrm[k], zr, emb + (size_t)k * DV);
                if (d < dmin || (d == dmin && k < kmin)) { dmin = d; kmin = k; }
            }
        }
    idxw[n] = kmin;
    out[(size_t)ZQN + 1 + n] = (float)kmin;
}

// E1b: full exact scan for overflowed n (one block per n, codes split
// across 256 threads -> no masked-lane serial scan).
__global__ __launch_bounds__(256) void vq_e1b(
    const float* __restrict__ z, const float* __restrict__ emb,
    const float* __restrict__ nrm, const u32* __restrict__ oflowCnt,
    const int* __restrict__ oflowList, int* __restrict__ idxw,
    float* __restrict__ out) {
    __shared__ u64 red[4];
    const int tid = threadIdx.x;
    const int nof = (int)*oflowCnt;
    for (int i = blockIdx.x; i < nof; i += gridDim.x) {
        const int n = oflowList[i];
        const float* zp = z + (size_t)(n >> 12) * 262144 + (n & 4095);
        float zr[DV];
#pragma unroll
        for (int d = 0; d < DV; ++d) zr[d] = zp[(size_t)d * 4096];
        double ad = 0.0;
#pragma unroll
        for (int d = 0; d < DV; ++d) ad = fma((double)zr[d], (double)zr[d], ad);
        const float A = (float)ad;
        u64 best = ~0ull;
        for (int k = tid; k < KC; k += 256) {
            float d = exact_d(A, nrm[k], zr, emb + (size_t)k * DV);
            u64 key = ((u64)__float_as_uint(d) << 32) | (u32)k;  // d>0
            if (key < best) best = key;
        }
#pragma unroll
        for (int off = 32; off > 0; off >>= 1) {
            u64 o = __shfl_down(best, off, 64);
            if (o < best) best = o;
        }
        if ((tid & 63) == 0) red[tid >> 6] = best;
        __syncthreads();
        if (tid == 0) {
            u64 b = red[0];
#pragma unroll
            for (int w = 1; w < 4; ++w) if (red[w] < b) b = red[w];
            int kmin = (int)(b & 0xffffffffu);
            idxw[n] = kmin;
            out[(size_t)ZQN + 1 + n] = (float)kmin;
        }
        __syncthreads();
    }
}

// E2: z_q gather-store + loss (overwrites d_out scratch region last).
__global__ __launch_bounds__(256) void vq_e2(
    const float* __restrict__ z, const float* __restrict__ emb,
    const int* __restrict__ idxw, float* __restrict__ out,
    double* __restrict__ lacc) {
    __shared__ double red[4];
    const int tid = threadIdx.x;
    const int n = blockIdx.x * 256 + tid;
    const int b = n >> 12, hw = n & 4095;
    const int kmin = idxw[n];
    const float* zp = z + (size_t)b * 262144 + hw;
    const float* erow = emb + (size_t)kmin * DV;
    double lsum = 0.0;
#pragma unroll
    for (int c = 0; c < DV; ++c) {
        float v = erow[c];
        out[(size_t)b * 262144 + (size_t)c * 4096 + hw] = v;   // coalesced per c
        double dv = (double)v - (double)zp[(size_t)c * 4096];
        lsum = fma(dv, dv, lsum);
    }
#pragma unroll
    for (int off = 32; off > 0; off >>= 1)
        lsum += __shfl_down(lsum, off, 64);
    if ((tid & 63) == 0) red[tid >> 6] = lsum;
    __syncthreads();
    if (tid == 0)
        atomicAdd(lacc, red[0] + red[1] + red[2] + red[3]);
}

__global__ void vq_fin(const double* __restrict__ lacc, float* __restrict__ out) {
    if (threadIdx.x == 0)
        out[ZQN] = (float)(1.25 * (*lacc) / (double)ZQN);
}

extern "C" void kernel_launch(void* const* d_in, const int* in_sizes, int n_in,
                              void* d_out, int out_size, void* d_ws, size_t ws_size,
                              hipStream_t stream) {
    const float* z   = (const float*)d_in[0];
    const float* emb = (const float*)d_in[1];
    float* out = (float*)d_out;

    // d_out scratch inside the z_q span (16.77 MB), consumed before E2:
    ushort* ebs  = (ushort*)d_out;                       // 1 MiB shuffled bf16
    u32*    cand = (u32*)((char*)d_out + 1048576);       // 12.6 MB (ends 13.6 MB)
    // ws scratch (~1.6 MB, under the proven 2.13 MB):
    double* lacc  = (double*)d_ws;                       // 8 B
    u32*    oflowCnt = (u32*)((char*)d_ws + 8);          // 4 B
    float*  nrm   = (float*)((char*)d_ws + 64);          // 32 KB
    u32*    cnt   = (u32*)((char*)d_ws + 32832);         // 1 MB
    int*    idxw  = (int*)((char*)d_ws + 1081408);       // 256 KB
    int*    oflowList = (int*)((char*)d_ws + 1343552);   // 256 KB

    vq_prep<<<256, 256, 0, stream>>>(emb, nrm, lacc, oflowCnt, ebs);
    vq_pass<<<NSPL * 256, 256, 0, stream>>>(z, ebs, cnt, cand);
    vq_e1<<<256, 256, 0, stream>>>(z, emb, nrm, cnt, cand, idxw, out,
                                   oflowCnt, oflowList);
    vq_e1b<<<128, 256, 0, stream>>>(z, emb, nrm, oflowCnt, oflowList, idxw, out);
    vq_e2<<<256, 256, 0, stream>>>(z, emb, idxw, out, lacc);
    vq_fin<<<1, 64, 0, stream>>>(lacc, out);
}

// Round 9
// 251.436 us; speedup vs baseline: 2.8035x; 2.8035x over previous
//
#include <hip/hip_runtime.h>

#define NTOT 65536      // 16*64*64 vectors
#define KC   8192       // codebook size
#define DV   64         // embedding dim
#define ZQN  4194304    // z_q elements
#define NSPL 4          // k-slices
#define KSL  2048       // codes per slice
#define TILE 128        // codes per LDS tile
#define NTILE 16        // tiles per slice
#define CAP2 16         // candidate entries per n (all slices; mean ~5)
#define SLA  44u        // append/filter slack, 2^-20 units (~4.2e-5 > TH 3e-5)
#define SLE  40u        // E1 cross-slice filter slack (~3.8e-5 > TH 3e-5)

typedef unsigned int u32;
typedef unsigned long long u64;
typedef unsigned short ushort;
typedef short short8 __attribute__((ext_vector_type(8)));   // 8 bf16
typedef float float4v __attribute__((ext_vector_type(4)));  // MFMA acc

__device__ __forceinline__ short f2bf(float x) {           // fp32->bf16 RNE
    u32 u = __float_as_uint(x);
    u32 r = (u + 0x7fffu + ((u >> 16) & 1u)) >> 16;
    return (short)r;
}

// Bit-exact numpy fp32 distance (VERIFIED bit-exact rounds 3-8):
// d = fl(fl(A+B) - 2*dot), dot in c_einsum SSE3-baseline order.
__device__ __forceinline__ float exact_d(float A, float B,
                                         const float* __restrict__ zr,
                                         const float* __restrict__ e) {
#pragma clang fp contract(off)
    float u0 = 0.f, u1 = 0.f, u2 = 0.f, u3 = 0.f;
#pragma unroll
    for (int i = 0; i < 4; ++i) {
        const int t = 16 * i;
        u0 = (zr[t+0]*e[t+0]) + ((zr[t+4]*e[t+4]) + ((zr[t+8]*e[t+8]) + ((zr[t+12]*e[t+12]) + u0)));
        u1 = (zr[t+1]*e[t+1]) + ((zr[t+5]*e[t+5]) + ((zr[t+9]*e[t+9]) + ((zr[t+13]*e[t+13]) + u1)));
        u2 = (zr[t+2]*e[t+2]) + ((zr[t+6]*e[t+6]) + ((zr[t+10]*e[t+10]) + ((zr[t+14]*e[t+14]) + u2)));
        u3 = (zr[t+3]*e[t+3]) + ((zr[t+7]*e[t+7]) + ((zr[t+11]*e[t+11]) + ((zr[t+15]*e[t+15]) + u3)));
    }
    float dot = (u0 + u1) + (u2 + u3);
    return (A + B) - (2.0f * dot);
}

// prep: fragment-order-shuffled bf16 codebook (verified rounds 7/8) +
// ||e||^2 + zero cnt/lacc/oflowCnt.
__global__ __launch_bounds__(256) void vq_prep(
    const float* __restrict__ emb, float* __restrict__ nrm,
    u32* __restrict__ cnt, double* __restrict__ lacc,
    u32* __restrict__ oflowCnt, ushort* __restrict__ ebs) {
    const int tid = blockIdx.x * 256 + threadIdx.x;    // 65536 threads
    const int t = tid >> 10, r = tid & 1023;
    const int s = r >> 7, r2 = r & 127, h = r2 >> 6, l = r2 & 63;
    const int q = l >> 4, c = l & 15;
    const float* src = emb + (size_t)((t * 128 + s * 16 + c) * 64 + h * 32 + q * 8);
    short8 v;
#pragma unroll
    for (int j = 0; j < 8; ++j) v[j] = f2bf(src[j]);
    *reinterpret_cast<short8*>(ebs + (size_t)tid * 8) = v;
    cnt[tid] = 0u;
    if (tid < KC) {
        double sacc = 0.0;
#pragma unroll
        for (int d = 0; d < DV; ++d) {
            double x = (double)emb[(size_t)tid * DV + d];
            sacc = fma(x, x, sacc);
        }
        nrm[tid] = (float)sacc;
    }
    if (tid == 0) { *lacc = 0.0; *oflowCnt = 0u; }
}

// Single MFMA screen pass. Per (lane, ns): register top-3 max-network over
// the 128 cell-maxes (enc16|cell9 packed u32, constant-indexed, no atomics
// in the hot loop). Slice end: cross-quad max, filter top-3 vs max-SLA,
// append survivors (mean ~1.3 per (n,slice)). Superset argument: a code
// within TH of the global max is dropped only if 4 same-quad cells sit in
// the TH window at the top (P~4e-7/n). Layouts verified rounds 5-8.
__global__ __launch_bounds__(256, 4) void vq_pass(
    const float* __restrict__ z, const ushort* __restrict__ ebs,
    u32* __restrict__ cnt, u32* __restrict__ cand) {
    __shared__ ushort tileS[TILE * DV];     // 16 KB
    const int tid = threadIdx.x;
    const int lane = tid & 63, wv = tid >> 6;
    const int nblk = blockIdx.x & 255, ks = blockIdx.x >> 8;
    const int nb = nblk * 256 + wv * 64;
    const int col = lane & 15, quad = lane >> 4;
    const int nlo = nb + col;

    // z B-frags in VGPRs (bitwise-identical conversion, rounds 5-8)
    short8 zf[4][2];
#pragma unroll
    for (int ns = 0; ns < 4; ++ns) {
        int n = nlo + ns * 16;
        const float* zp = z + (size_t)(n >> 12) * 262144 + (n & 4095);
#pragma unroll
        for (int t2 = 0; t2 < 2; ++t2)
#pragma unroll
            for (int j = 0; j < 8; ++j)
                zf[ns][t2][j] = f2bf(zp[(size_t)(t2 * 32 + quad * 8 + j) * 4096]);
    }

    u32 r0[4] = {0, 0, 0, 0}, r1[4] = {0, 0, 0, 0}, r2[4] = {0, 0, 0, 0};
    const char* gs = (const char*)ebs + (size_t)ks * (KSL * DV * 2);

    int4 pre[4];
#pragma unroll
    for (int j = 0; j < 4; ++j)
        pre[j] = *reinterpret_cast<const int4*>(gs + j * 4096 + tid * 16);

    for (int t = 0; t < NTILE; ++t) {
        __syncthreads();
#pragma unroll
        for (int j = 0; j < 4; ++j)
            *reinterpret_cast<int4*>((char*)tileS + j * 4096 + tid * 16) = pre[j];
        __syncthreads();
        if (t < NTILE - 1) {
#pragma unroll
            for (int j = 0; j < 4; ++j)
                pre[j] = *reinterpret_cast<const int4*>(
                    gs + (size_t)(t + 1) * 16384 + j * 4096 + tid * 16);
        }
#pragma unroll
        for (int s = 0; s < 8; ++s) {
            const char* tb = (const char*)tileS + s * 2048;
            short8 a0 = *reinterpret_cast<const short8*>(tb + lane * 16);
            short8 a1 = *reinterpret_cast<const short8*>(tb + 1024 + lane * 16);
            // enc low half: sign-offset | step(7b)<<2 | quad(2b)
            const u32 lowc = 0x80000000u + (u32)((((t << 3) | s) << 2) | quad);
#pragma unroll
            for (int ns = 0; ns < 4; ++ns) {
                float4v acc = {0.f, 0.f, 0.f, 0.f};
                acc = __builtin_amdgcn_mfma_f32_16x16x32_bf16(a0, zf[ns][0], acc, 0, 0, 0);
                acc = __builtin_amdgcn_mfma_f32_16x16x32_bf16(a1, zf[ns][1], acc, 0, 0, 0);
                float m4 = fmaxf(fmaxf(acc[0], acc[1]), fmaxf(acc[2], acc[3]));
                // |dot| <= ||z||*||e|| <= 10.4*9.8e-4 -> enc16 in [22068,43468]: no clamp
                u32 e = ((u32)(int)(m4 * 1048576.0f) << 16) + lowc;
                // top-3 max-network (5 ops, sorted invariant r0>=r1>=r2)
                u32 x  = min(r0[ns], e);
                r0[ns] = max(r0[ns], e);
                u32 y  = min(r1[ns], x);
                r1[ns] = max(r1[ns], x);
                r2[ns] = max(r2[ns], y);
            }
        }
    }

    // slice-end: cross-quad max per n, filter top-3, append survivors
#pragma unroll
    for (int ns = 0; ns < 4; ++ns) {
        u32 m = r0[ns];
        m = max(m, __shfl_xor(m, 16));
        m = max(m, __shfl_xor(m, 32));
        const u32 thr = (m & 0xffff0000u) - (SLA << 16);   // enc >= 22068 > SLA
        const int n = nlo + ns * 16;
        const u32 tag = (u32)ks << 9;                      // slice id in bits 9-10
        if (r0[ns] >= thr) {
            u32 p = atomicAdd(&cnt[n], 1u);
            if (p < CAP2) cand[(size_t)n * CAP2 + p] = r0[ns] | tag;
        }
        if (r1[ns] >= thr) {
            u32 p = atomicAdd(&cnt[n], 1u);
            if (p < CAP2) cand[(size_t)n * CAP2 + p] = r1[ns] | tag;
        }
        if (r2[ns] >= thr) {
            u32 p = atomicAdd(&cnt[n], 1u);
            if (p < CAP2) cand[(size_t)n * CAP2 + p] = r2[ns] | tag;
        }
    }
}

// E1: cross-slice enc filter, exact (numpy-bit-identical) rescore -> index.
__global__ __launch_bounds__(256) void vq_e1(
    const float* __restrict__ z, const float* __restrict__ emb,
    const float* __restrict__ nrm, const u32* __restrict__ cnt,
    const u32* __restrict__ cand, int* __restrict__ idxw,
    float* __restrict__ out, u32* __restrict__ oflowCnt,
    int* __restrict__ oflowList) {
    const int n = blockIdx.x * 256 + threadIdx.x;
    u32 c = cnt[n];
    if (c > CAP2) {                                   // ~never (mean 5, cap 16)
        u32 p = atomicAdd(oflowCnt, 1u);
        oflowList[p] = n;
        idxw[n] = 0;
        out[(size_t)ZQN + 1 + n] = 0.f;               // E1b overwrites
        return;
    }
    u32 emax = 0u;
    for (u32 j = 0; j < c; ++j) {
        u32 e = cand[(size_t)n * CAP2 + j];
        if (e > emax) emax = e;
    }
    const u32 ethr = (emax & 0xffff0000u) - (SLE << 16);

    const float* zp = z + (size_t)(n >> 12) * 262144 + (n & 4095);
    float zr[DV];
#pragma unroll
    for (int d = 0; d < DV; ++d) zr[d] = zp[(size_t)d * 4096];
    double ad = 0.0;
#pragma unroll
    for (int d = 0; d < DV; ++d) ad = fma((double)zr[d], (double)zr[d], ad);
    const float A = (float)ad;

    float dmin = 1e30f;
    int kmin = 0x7fffffff;
    for (u32 j = 0; j < c; ++j) {
        u32 e = cand[(size_t)n * CAP2 + j];
        if (e < ethr) continue;                        // filtered (~1.3 survive)
        int s    = (int)(e >> 9) & 3;
        int step = (int)(e >> 2) & 127;
        int q    = (int)e & 3;
        int base = s * KSL + step * 16 + q * 4;
#pragma unroll
        for (int r = 0; r < 4; ++r) {
            int k = base + r;
            float d = exact_d(A, nrm[k], zr, emb + (size_t)k * DV);
            if (d < dmin || (d == dmin && k < kmin)) { dmin = d; kmin = k; }
        }
    }
    idxw[n] = kmin;
    out[(size_t)ZQN + 1 + n] = (float)kmin;
}

// E1b: full exact scan for overflowed n (one block per n; verified round 8).
__global__ __launch_bounds__(256) void vq_e1b(
    const float* __restrict__ z, const float* __restrict__ emb,
    const float* __restrict__ nrm, const u32* __restrict__ oflowCnt,
    const int* __restrict__ oflowList, int* __restrict__ idxw,
    float* __restrict__ out) {
    __shared__ u64 red[4];
    const int tid = threadIdx.x;
    const int nof = (int)*oflowCnt;
    for (int i = blockIdx.x; i < nof; i += gridDim.x) {
        const int n = oflowList[i];
        const float* zp = z + (size_t)(n >> 12) * 262144 + (n & 4095);
        float zr[DV];
#pragma unroll
        for (int d = 0; d < DV; ++d) zr[d] = zp[(size_t)d * 4096];
        double ad = 0.0;
#pragma unroll
        for (int d = 0; d < DV; ++d) ad = fma((double)zr[d], (double)zr[d], ad);
        const float A = (float)ad;
        u64 best = ~0ull;
        for (int k = tid; k < KC; k += 256) {
            float d = exact_d(A, nrm[k], zr, emb + (size_t)k * DV);
            u64 key = ((u64)__float_as_uint(d) << 32) | (u32)k;  // d>0
            if (key < best) best = key;
        }
#pragma unroll
        for (int off = 32; off > 0; off >>= 1) {
            u64 o = __shfl_down(best, off, 64);
            if (o < best) best = o;
        }
        if ((tid & 63) == 0) red[tid >> 6] = best;
        __syncthreads();
        if (tid == 0) {
            u64 b = red[0];
#pragma unroll
            for (int w = 1; w < 4; ++w) if (red[w] < b) b = red[w];
            int kmin = (int)(b & 0xffffffffu);
            idxw[n] = kmin;
            out[(size_t)ZQN + 1 + n] = (float)kmin;
        }
        __syncthreads();
    }
}

// E2: z_q gather-store + loss (overwrites d_out scratch region last).
__global__ __launch_bounds__(256) void vq_e2(
    const float* __restrict__ z, const float* __restrict__ emb,
    const int* __restrict__ idxw, float* __restrict__ out,
    double* __restrict__ lacc) {
    __shared__ double red[4];
    const int tid = threadIdx.x;
    const int n = blockIdx.x * 256 + tid;
    const int b = n >> 12, hw = n & 4095;
    const int kmin = idxw[n];
    const float* zp = z + (size_t)b * 262144 + hw;
    const float* erow = emb + (size_t)kmin * DV;
    double lsum = 0.0;
#pragma unroll
    for (int c = 0; c < DV; ++c) {
        float v = erow[c];
        out[(size_t)b * 262144 + (size_t)c * 4096 + hw] = v;   // coalesced per c
        double dv = (double)v - (double)zp[(size_t)c * 4096];
        lsum = fma(dv, dv, lsum);
    }
#pragma unroll
    for (int off = 32; off > 0; off >>= 1)
        lsum += __shfl_down(lsum, off, 64);
    if ((tid & 63) == 0) red[tid >> 6] = lsum;
    __syncthreads();
    if (tid == 0)
        atomicAdd(lacc, red[0] + red[1] + red[2] + red[3]);
}

__global__ void vq_fin(const double* __restrict__ lacc, float* __restrict__ out) {
    if (threadIdx.x == 0)
        out[ZQN] = (float)(1.25 * (*lacc) / (double)ZQN);
}

extern "C" void kernel_launch(void* const* d_in, const int* in_sizes, int n_in,
                              void* d_out, int out_size, void* d_ws, size_t ws_size,
                              hipStream_t stream) {
    const float* z   = (const float*)d_in[0];
    const float* emb = (const float*)d_in[1];
    float* out = (float*)d_out;

    // d_out scratch inside the z_q span (16.77 MB), consumed before E2:
    ushort* ebs  = (ushort*)d_out;                       // 1 MiB shuffled bf16
    u32*    cand = (u32*)((char*)d_out + 1048576);       // 4 MiB (ends 5 MiB)
    // ws scratch (~820 KB, under the proven 2.13 MB):
    double* lacc  = (double*)d_ws;                       // 8 B
    u32*    oflowCnt = (u32*)((char*)d_ws + 8);          // 4 B
    float*  nrm   = (float*)((char*)d_ws + 64);          // 32 KB
    u32*    cnt   = (u32*)((char*)d_ws + 32832);         // 256 KB
    int*    idxw  = (int*)((char*)d_ws + 294976);        // 256 KB
    int*    oflowList = (int*)((char*)d_ws + 557120);    // 256 KB

    vq_prep<<<256, 256, 0, stream>>>(emb, nrm, cnt, lacc, oflowCnt, ebs);
    vq_pass<<<NSPL * 256, 256, 0, stream>>>(z, ebs, cnt, cand);
    vq_e1<<<256, 256, 0, stream>>>(z, emb, nrm, cnt, cand, idxw, out,
                                   oflowCnt, oflowList);
    vq_e1b<<<128, 256, 0, stream>>>(z, emb, nrm, oflowCnt, oflowList, idxw, out);
    vq_e2<<<256, 256, 0, stream>>>(z, emb, idxw, out, lacc);
    vq_fin<<<1, 64, 0, stream>>>(lacc, out);
}

// Round 10
// 245.132 us; speedup vs baseline: 2.8756x; 1.0257x over previous
//
#include <hip/hip_runtime.h>

#define NTOT 65536      // 16*64*64 vectors
#define KC   8192       // codebook size
#define DV   64         // embedding dim
#define ZQN  4194304    // z_q elements
#define NSPL 4          // k-slices
#define KSL  2048       // codes per slice
#define TILE 128        // codes per LDS tile
#define NTILE 16        // tiles per slice
#define CAP2 16         // candidate entries per n (all slices; mean ~5)
#define SLA  44u        // append filter slack, 2^-20 units (~4.2e-5 > TH 3e-5)
#define SLE  40u        // E1 cross-slice filter slack (~3.8e-5 > TH 3e-5)

typedef unsigned int u32;
typedef unsigned long long u64;
typedef unsigned short ushort;
typedef short short8 __attribute__((ext_vector_type(8)));   // 8 bf16
typedef float float4v __attribute__((ext_vector_type(4)));  // MFMA acc

__device__ __forceinline__ short f2bf(float x) {           // fp32->bf16 RNE
    u32 u = __float_as_uint(x);
    u32 r = (u + 0x7fffu + ((u >> 16) & 1u)) >> 16;
    return (short)r;
}

// Bit-exact numpy fp32 distance (VERIFIED bit-exact rounds 3-9):
// d = fl(fl(A+B) - 2*dot), dot in c_einsum SSE3-baseline order.
__device__ __forceinline__ float exact_d(float A, float B,
                                         const float* __restrict__ zr,
                                         const float* __restrict__ e) {
#pragma clang fp contract(off)
    float u0 = 0.f, u1 = 0.f, u2 = 0.f, u3 = 0.f;
#pragma unroll
    for (int i = 0; i < 4; ++i) {
        const int t = 16 * i;
        u0 = (zr[t+0]*e[t+0]) + ((zr[t+4]*e[t+4]) + ((zr[t+8]*e[t+8]) + ((zr[t+12]*e[t+12]) + u0)));
        u1 = (zr[t+1]*e[t+1]) + ((zr[t+5]*e[t+5]) + ((zr[t+9]*e[t+9]) + ((zr[t+13]*e[t+13]) + u1)));
        u2 = (zr[t+2]*e[t+2]) + ((zr[t+6]*e[t+6]) + ((zr[t+10]*e[t+10]) + ((zr[t+14]*e[t+14]) + u2)));
        u3 = (zr[t+3]*e[t+3]) + ((zr[t+7]*e[t+7]) + ((zr[t+11]*e[t+11]) + ((zr[t+15]*e[t+15]) + u3)));
    }
    float dot = (u0 + u1) + (u2 + u3);
    return (A + B) - (2.0f * dot);
}

// prep: fragment-order-shuffled bf16 codebook (verified r7-r9) + ||e||^2 +
// zero cnt/lacc/oflowCnt.
__global__ __launch_bounds__(256) void vq_prep(
    const float* __restrict__ emb, float* __restrict__ nrm,
    u32* __restrict__ cnt, double* __restrict__ lacc,
    u32* __restrict__ oflowCnt, ushort* __restrict__ ebs) {
    const int tid = blockIdx.x * 256 + threadIdx.x;    // 65536 threads
    const int t = tid >> 10, r = tid & 1023;
    const int s = r >> 7, r2 = r & 127, h = r2 >> 6, l = r2 & 63;
    const int q = l >> 4, c = l & 15;
    const float* src = emb + (size_t)((t * 128 + s * 16 + c) * 64 + h * 32 + q * 8);
    short8 v;
#pragma unroll
    for (int j = 0; j < 8; ++j) v[j] = f2bf(src[j]);
    *reinterpret_cast<short8*>(ebs + (size_t)tid * 8) = v;
    cnt[tid] = 0u;
    if (tid < KC) {
        double sacc = 0.0;
#pragma unroll
        for (int d = 0; d < DV; ++d) {
            double x = (double)emb[(size_t)tid * DV + d];
            sacc = fma(x, x, sacc);
        }
        nrm[tid] = (float)sacc;
    }
    if (tid == 0) { *lacc = 0.0; *oflowCnt = 0u; }
}

// Single MFMA screen pass (r9 structure), fixes: (a) waves_per_eu(4,4) pins
// VGPR budget to 128 -> no scratch spill of pre[]/zf; (b) top-3 update per
// 2-step group (cell = 8 codes) halves the enc+network VALU.
__global__ __launch_bounds__(256) __attribute__((amdgpu_waves_per_eu(4, 4)))
void vq_pass(const float* __restrict__ z, const ushort* __restrict__ ebs,
             u32* __restrict__ cnt, u32* __restrict__ cand) {
    __shared__ ushort tileS[TILE * DV];     // 16 KB
    const int tid = threadIdx.x;
    const int lane = tid & 63;
    const int nblk = blockIdx.x & 255, ks = blockIdx.x >> 8;
    const int nb = nblk * 256 + (tid >> 6) * 64;
    const int col = lane & 15, quad = lane >> 4;
    const int nlo = nb + col;

    // z B-frags in VGPRs (bitwise-identical conversion, rounds 5-9)
    short8 zf[4][2];
#pragma unroll
    for (int ns = 0; ns < 4; ++ns) {
        int n = nlo + ns * 16;
        const float* zp = z + (size_t)(n >> 12) * 262144 + (n & 4095);
#pragma unroll
        for (int t2 = 0; t2 < 2; ++t2)
#pragma unroll
            for (int j = 0; j < 8; ++j)
                zf[ns][t2][j] = f2bf(zp[(size_t)(t2 * 32 + quad * 8 + j) * 4096]);
    }

    u32 r0[4] = {0, 0, 0, 0}, r1[4] = {0, 0, 0, 0}, r2[4] = {0, 0, 0, 0};
    const char* gs = (const char*)ebs + (size_t)ks * (KSL * DV * 2);

    int4 pre[4];
#pragma unroll
    for (int j = 0; j < 4; ++j)
        pre[j] = *reinterpret_cast<const int4*>(gs + j * 4096 + tid * 16);

    for (int t = 0; t < NTILE; ++t) {
        __syncthreads();
#pragma unroll
        for (int j = 0; j < 4; ++j)
            *reinterpret_cast<int4*>((char*)tileS + j * 4096 + tid * 16) = pre[j];
        __syncthreads();
        if (t < NTILE - 1) {
#pragma unroll
            for (int j = 0; j < 4; ++j)
                pre[j] = *reinterpret_cast<const int4*>(
                    gs + (size_t)(t + 1) * 16384 + j * 4096 + tid * 16);
        }
#pragma unroll
        for (int g2 = 0; g2 < 4; ++g2) {            // 2 steps = 32 codes/group
            const char* tb = (const char*)tileS + g2 * 4096;
            short8 a00 = *reinterpret_cast<const short8*>(tb + lane * 16);
            short8 a01 = *reinterpret_cast<const short8*>(tb + 1024 + lane * 16);
            short8 a10 = *reinterpret_cast<const short8*>(tb + 2048 + lane * 16);
            short8 a11 = *reinterpret_cast<const short8*>(tb + 3072 + lane * 16);
            // enc low: sign-offset | group6<<2 | quad2   (bits 8..15 zero)
            const u32 lowc = 0x80000000u + (u32)(((t * 4 + g2) << 2) | quad);
#pragma unroll
            for (int ns = 0; ns < 4; ++ns) {
                float4v acc0 = {0.f, 0.f, 0.f, 0.f};
                float4v acc1 = {0.f, 0.f, 0.f, 0.f};
                acc0 = __builtin_amdgcn_mfma_f32_16x16x32_bf16(a00, zf[ns][0], acc0, 0, 0, 0);
                acc0 = __builtin_amdgcn_mfma_f32_16x16x32_bf16(a01, zf[ns][1], acc0, 0, 0, 0);
                acc1 = __builtin_amdgcn_mfma_f32_16x16x32_bf16(a10, zf[ns][0], acc1, 0, 0, 0);
                acc1 = __builtin_amdgcn_mfma_f32_16x16x32_bf16(a11, zf[ns][1], acc1, 0, 0, 0);
                float m = fmaxf(fmaxf(fmaxf(acc0[0], acc0[1]), fmaxf(acc0[2], acc0[3])),
                                fmaxf(fmaxf(acc1[0], acc1[1]), fmaxf(acc1[2], acc1[3])));
                // |dot| < 0.0105 -> |int| < 11010 < 2^15: bias keeps monotone
                u32 e = ((u32)(int)(m * 1048576.0f) << 16) + lowc;
                u32 x  = min(r0[ns], e);            // top-3 network (5 ops)
                r0[ns] = max(r0[ns], e);
                u32 y  = min(r1[ns], x);
                r1[ns] = max(r1[ns], x);
                r2[ns] = max(r2[ns], y);
            }
        }
    }

    // slice-end: cross-quad max per n, filter top-3, append survivors
#pragma unroll
    for (int ns = 0; ns < 4; ++ns) {
        u32 m = r0[ns];
        m = max(m, __shfl_xor(m, 16));
        m = max(m, __shfl_xor(m, 32));
        const u32 thr = (m & 0xffff0000u) - (SLA << 16);
        const int n = nlo + ns * 16;
        const u32 tag = (u32)ks << 8;               // slice id, bits 8-9
        if (r0[ns] >= thr) {
            u32 p = atomicAdd(&cnt[n], 1u);
            if (p < CAP2) cand[(size_t)n * CAP2 + p] = r0[ns] | tag;
        }
        if (r1[ns] >= thr) {
            u32 p = atomicAdd(&cnt[n], 1u);
            if (p < CAP2) cand[(size_t)n * CAP2 + p] = r1[ns] | tag;
        }
        if (r2[ns] >= thr) {
            u32 p = atomicAdd(&cnt[n], 1u);
            if (p < CAP2) cand[(size_t)n * CAP2 + p] = r2[ns] | tag;
        }
    }
}

// E1: cross-slice enc filter + exact (numpy-bit-identical) rescore.
// 4 threads per n (candidates j4::4); exact u64 (d,k)-key min merged via
// shfl -> identical winner to the serial version (d>0 so fp32 bits order).
__global__ __launch_bounds__(256) void vq_e1(
    const float* __restrict__ z, const float* __restrict__ emb,
    const float* __restrict__ nrm, const u32* __restrict__ cnt,
    const u32* __restrict__ cand, int* __restrict__ idxw,
    float* __restrict__ out, u32* __restrict__ oflowCnt,
    int* __restrict__ oflowList) {
    const int gid = blockIdx.x * 256 + threadIdx.x;   // 262144 threads
    const int n = gid >> 2, j4 = gid & 3;
    u32 c = cnt[n];
    if (c > CAP2) {                                   // ~never
        if (j4 == 0) {
            u32 p = atomicAdd(oflowCnt, 1u);
            oflowList[p] = n;
            idxw[n] = 0;
            out[(size_t)ZQN + 1 + n] = 0.f;           // E1b overwrites
        }
        return;
    }
    u32 emax = 0u;
    for (u32 j = 0; j < c; ++j) {
        u32 e = cand[(size_t)n * CAP2 + j];
        if (e > emax) emax = e;
    }
    const u32 ethr = (emax & 0xffff0000u) - (SLE << 16);

    const float* zp = z + (size_t)(n >> 12) * 262144 + (n & 4095);
    float zr[DV];
#pragma unroll
    for (int d = 0; d < DV; ++d) zr[d] = zp[(size_t)d * 4096];
    double ad = 0.0;
#pragma unroll
    for (int d = 0; d < DV; ++d) ad = fma((double)zr[d], (double)zr[d], ad);
    const float A = (float)ad;

    float dmin = 1e30f;
    int kmin = 0x7fffffff;
    for (u32 j = (u32)j4; j < c; j += 4) {
        u32 e = cand[(size_t)n * CAP2 + j];
        if (e < ethr) continue;                       // filtered
        int s   = (int)(e >> 8) & 3;
        int grp = (int)(e >> 2) & 63;
        int q   = (int)e & 3;
        int base = s * KSL + grp * 32 + q * 4;        // 8 codes: st*16 + r
#pragma unroll
        for (int st = 0; st < 2; ++st)
#pragma unroll
            for (int r = 0; r < 4; ++r) {
                int k = base + st * 16 + r;
                float d = exact_d(A, nrm[k], zr, emb + (size_t)k * DV);
                if (d < dmin || (d == dmin && k < kmin)) { dmin = d; kmin = k; }
            }
    }
    u64 key = ((u64)__float_as_uint(dmin) << 32) | (u32)kmin;   // d > 0
    u64 o1 = __shfl_xor(key, 1, 64); if (o1 < key) key = o1;
    u64 o2 = __shfl_xor(key, 2, 64); if (o2 < key) key = o2;
    if (j4 == 0) {
        int km = (int)(key & 0xffffffffu);
        idxw[n] = km;
        out[(size_t)ZQN + 1 + n] = (float)km;
    }
}

// E1b: full exact scan for overflowed n (one block per n; verified r8/r9).
__global__ __launch_bounds__(256) void vq_e1b(
    const float* __restrict__ z, const float* __restrict__ emb,
    const float* __restrict__ nrm, const u32* __restrict__ oflowCnt,
    const int* __restrict__ oflowList, int* __restrict__ idxw,
    float* __restrict__ out) {
    __shared__ u64 red[4];
    const int tid = threadIdx.x;
    const int nof = (int)*oflowCnt;
    for (int i = blockIdx.x; i < nof; i += gridDim.x) {
        const int n = oflowList[i];
        const float* zp = z + (size_t)(n >> 12) * 262144 + (n & 4095);
        float zr[DV];
#pragma unroll
        for (int d = 0; d < DV; ++d) zr[d] = zp[(size_t)d * 4096];
        double ad = 0.0;
#pragma unroll
        for (int d = 0; d < DV; ++d) ad = fma((double)zr[d], (double)zr[d], ad);
        const float A = (float)ad;
        u64 best = ~0ull;
        for (int k = tid; k < KC; k += 256) {
            float d = exact_d(A, nrm[k], zr, emb + (size_t)k * DV);
            u64 key = ((u64)__float_as_uint(d) << 32) | (u32)k;
            if (key < best) best = key;
        }
#pragma unroll
        for (int off = 32; off > 0; off >>= 1) {
            u64 o = __shfl_down(best, off, 64);
            if (o < best) best = o;
        }
        if ((tid & 63) == 0) red[tid >> 6] = best;
        __syncthreads();
        if (tid == 0) {
            u64 b = red[0];
#pragma unroll
            for (int w = 1; w < 4; ++w) if (red[w] < b) b = red[w];
            int kmin = (int)(b & 0xffffffffu);
            idxw[n] = kmin;
            out[(size_t)ZQN + 1 + n] = (float)kmin;
        }
        __syncthreads();
    }
}

// E2: z_q gather-store + loss. 4 waves split the 64 channels; lanes hold 64
// consecutive n -> 256 B coalesced z reads and out writes.
__global__ __launch_bounds__(256) void vq_e2(
    const float* __restrict__ z, const float* __restrict__ emb,
    const int* __restrict__ idxw, float* __restrict__ out,
    double* __restrict__ lacc) {
    __shared__ double red[4];
    const int tid = threadIdx.x;
    const int n = blockIdx.x * 64 + (tid & 63);
    const int part = tid >> 6;                        // 16 channels per wave
    const int b = n >> 12, hw = n & 4095;
    const int kmin = idxw[n];
    const float* zp = z + (size_t)b * 262144 + hw;
    const float4* er4 = (const float4*)(emb + (size_t)kmin * DV + part * 16);
    double lsum = 0.0;
#pragma unroll
    for (int i4 = 0; i4 < 4; ++i4) {
        float4 ev = er4[i4];
#pragma unroll
        for (int u = 0; u < 4; ++u) {
            int c = part * 16 + i4 * 4 + u;
            float v = (u == 0) ? ev.x : (u == 1) ? ev.y : (u == 2) ? ev.z : ev.w;
            out[(size_t)b * 262144 + (size_t)c * 4096 + hw] = v;
            double dv = (double)v - (double)zp[(size_t)c * 4096];
            lsum = fma(dv, dv, lsum);
        }
    }
#pragma unroll
    for (int off = 32; off > 0; off >>= 1)
        lsum += __shfl_down(lsum, off, 64);
    if ((tid & 63) == 0) red[tid >> 6] = lsum;
    __syncthreads();
    if (tid == 0)
        atomicAdd(lacc, red[0] + red[1] + red[2] + red[3]);
}

__global__ void vq_fin(const double* __restrict__ lacc, float* __restrict__ out) {
    if (threadIdx.x == 0)
        out[ZQN] = (float)(1.25 * (*lacc) / (double)ZQN);
}

extern "C" void kernel_launch(void* const* d_in, const int* in_sizes, int n_in,
                              void* d_out, int out_size, void* d_ws, size_t ws_size,
                              hipStream_t stream) {
    const float* z   = (const float*)d_in[0];
    const float* emb = (const float*)d_in[1];
    float* out = (float*)d_out;

    // d_out scratch inside the z_q span (16.77 MB), consumed before E2:
    ushort* ebs  = (ushort*)d_out;                       // 1 MiB shuffled bf16
    u32*    cand = (u32*)((char*)d_out + 1048576);       // 4 MiB (ends 5 MiB)
    // ws scratch (~820 KB, under the proven 2.13 MB):
    double* lacc  = (double*)d_ws;                       // 8 B
    u32*    oflowCnt = (u32*)((char*)d_ws + 8);          // 4 B
    float*  nrm   = (float*)((char*)d_ws + 64);          // 32 KB
    u32*    cnt   = (u32*)((char*)d_ws + 32832);         // 256 KB
    int*    idxw  = (int*)((char*)d_ws + 294976);        // 256 KB
    int*    oflowList = (int*)((char*)d_ws + 557120);    // 256 KB

    vq_prep<<<256, 256, 0, stream>>>(emb, nrm, cnt, lacc, oflowCnt, ebs);
    vq_pass<<<NSPL * 256, 256, 0, stream>>>(z, ebs, cnt, cand);
    vq_e1<<<1024, 256, 0, stream>>>(z, emb, nrm, cnt, cand, idxw, out,
                                    oflowCnt, oflowList);
    vq_e1b<<<128, 256, 0, stream>>>(z, emb, nrm, oflowCnt, oflowList, idxw, out);
    vq_e2<<<1024, 256, 0, stream>>>(z, emb, idxw, out, lacc);
    vq_fin<<<1, 64, 0, stream>>>(lacc, out);
}